// Round 10
// baseline (130.445 us; speedup 1.0000x reference)
//
#include <hip/hip_runtime.h>

// N=100000, E=3200000, H=256, G=128.
// R16: halve partial-slab traffic at constant occupancy. Evidence chain:
//  - R9/R10: global f32 atomics memory-side at ANY scope (~20G/s) -> LDS agg.
//  - R11: grid.sync ~50us -> no cooperative fusion; harness 256MiB poison
//    fills (~88us, independent of our ws usage) sit INSIDE the timed window.
//  - R12->R15: occupancy 34->100% + predication/ILP: 126.2 -> 119.8us.
//    Edges are L3-resident across iterations (p1 FETCH 14MB < 25.6MB edges)
//    -> dst-chunk redundancy is L2/L3-absorbed, nearly free.
//  - Partial buffer = N*CHK*4B regardless of RNG -> shrink CHK, grow RNG.
// This round: RNG 8->16, CHK 64->32, BLK1=1024. Grid stays 512 = 2 blk/CU
// x 16 waves = 32 waves/CU (100%). LDS slab 6272 words = 25KB. Partial
// round-trip 25.7 -> 12.8MB each way; p2 sums 32 slabs; src-quad skip rate
// (15/16)^4 = 77%. Per-XCD chunk footprint: 4 chunks x 800KB = 3.2MB < 4MB.
//  P1: block (r,j) streams edge chunk j, filters dst in range r (1-compare
//      unsigned test), acc[dst-lo] += x[src] (LDS f32 atomics), slab ->
//      partial[r*CHK+j] coalesced. Block 0 zeroes header for P2.
//  P2: a = sum_j partial[r][j][li] (32 coalesced strided reads), collapsed
//      MLP f(a)=sum_k relu(a*Wl[k]+bl[k])*Wo[k], per-graph LDS pooling,
//      sparse device atomics, ticket epilogue -> relu(mean + b_out).

#define GMAX 128       // max graphs
#define HMAX 256       // max hidden dim
#define RNG  16        // node ranges (LDS-sized)
#define CHK  32        // edge chunks (%8==0 for XCD affinity; grid=512)
#define BLK1 1024      // p1 threads (16 waves; 2 blocks/CU = 32 waves = 100%)
#define RLDS 6272      // LDS accumulator words per range (>= ceil(N/RNG), %64==0)
#define HDRW 272       // header words (gsum,gcnt,done + pad to 16B)

// ---------------- main path ----------------

__global__ __launch_bounds__(BLK1, 8) void p1_scatter(
    const int* __restrict__ ei, const float* __restrict__ x,
    float* __restrict__ partial, float* __restrict__ gsum,
    float* __restrict__ gcnt, unsigned* __restrict__ done,
    int E, int N, int RANGE, int QpC) {
  __shared__ __align__(16) float acc[RLDS];
  int tid = threadIdx.x, blk = blockIdx.x;
  int r = blk / CHK;         // node range id   [0,RNG)
  int j = blk % CHK;         // edge chunk id   [0,CHK) -> XCD = j%8
  for (int i = tid; i < RLDS; i += BLK1) acc[i] = 0.f;
  if (blk == 0) {            // zero epilogue state for P2 (ws is poisoned)
    if (tid < GMAX) { gsum[tid] = 0.f; gcnt[tid] = 0.f; }
    if (tid == 0) done[0] = 0u;
  }
  __syncthreads();

  int lo = r * RANGE;
  unsigned span = (unsigned)(min(lo + RANGE, N) - lo);
  int Q = E >> 2;
  int q0 = j * QpC, q1 = min(q0 + QpC, Q);
  const int4* s4 = (const int4*)ei;
  const int4* d4 = (const int4*)(ei + E);
#pragma unroll 4
  for (int q = q0 + tid; q < q1; q += BLK1) {
    int4 d = d4[q];
    unsigned ux = (unsigned)(d.x - lo), uy = (unsigned)(d.y - lo);
    unsigned uz = (unsigned)(d.z - lo), uw = (unsigned)(d.w - lo);
    if ((ux < span) | (uy < span) | (uz < span) | (uw < span)) {
      int4 s = s4[q];        // src quad only when some lane-edge passes (23%)
      if (ux < span) atomicAdd(&acc[ux], x[s.x]);
      if (uy < span) atomicAdd(&acc[uy], x[s.y]);
      if (uz < span) atomicAdd(&acc[uz], x[s.z]);
      if (uw < span) atomicAdd(&acc[uw], x[s.w]);
    }
  }
  if (j == 0) {              // tail edges (E % 4): the RNG j==0 blocks filter
    for (int e = (Q << 2) + tid; e < E; e += BLK1) {
      unsigned u = (unsigned)(ei[E + e] - lo);
      if (u < span) atomicAdd(&acc[u], x[ei[e]]);
    }
  }
  __syncthreads();

  // coalesced slab dump (full RLDS incl zero pad; P2 reads only li < RANGE)
  float4* dst = (float4*)(partial + (size_t)blk * RLDS);
  const float4* a4 = (const float4*)acc;
  for (int i = tid; i < RLDS / 4; i += BLK1) dst[i] = a4[i];
}

__global__ __launch_bounds__(256, 4) void p2_node(
    const float* __restrict__ partial, const int* __restrict__ batch,
    const float* __restrict__ Wl, const float* __restrict__ bl,
    const float* __restrict__ Wo, const float* __restrict__ bo,
    float* __restrict__ gsum, float* __restrict__ gcnt,
    unsigned* __restrict__ done, float* __restrict__ out,
    int N, int H, int G, int RANGE, int BPR) {
  __shared__ float sWl[HMAX], sbl[HMAX], sWo[HMAX];
  __shared__ float ls[GMAX], lc[GMAX];
  __shared__ unsigned ticket;
  int tid = threadIdx.x, blk = blockIdx.x;
  if (tid < H) { sWl[tid] = Wl[tid]; sbl[tid] = bl[tid]; sWo[tid] = Wo[tid]; }
  if (tid < GMAX) { ls[tid] = 0.f; lc[tid] = 0.f; }
  __syncthreads();

  int r = blk / BPR;
  int li = (blk % BPR) * 256 + tid;
  int node = r * RANGE + li;
  if (li < RANGE && node < N) {
    // CHK-way partial sum: coalesced across lanes, 16-deep ILP across slabs
    const float* p = partial + (size_t)(r * CHK) * RLDS + li;
    float a = 0.f;
#pragma unroll 16
    for (int c = 0; c < CHK; ++c) a += p[(size_t)c * RLDS];
    float f = 0.f;
#pragma unroll 8
    for (int k = 0; k < H; ++k) {
      float hh = fmaf(a, sWl[k], sbl[k]);
      f = fmaf(fmaxf(hh, 0.f), sWo[k], f);
    }
    int g = batch[node];
    atomicAdd(&ls[g], f);
    atomicAdd(&lc[g], 1.f);
  }
  __syncthreads();
  if (tid < GMAX && lc[tid] != 0.f) {
    atomicAdd(&gsum[tid], ls[tid]);   // sparse: batch sorted -> ~1-2 graphs/blk
    atomicAdd(&gcnt[tid], lc[tid]);
  }
  __syncthreads();
  if (tid == 0)
    ticket = __hip_atomic_fetch_add(done, 1u, __ATOMIC_ACQ_REL,
                                    __HIP_MEMORY_SCOPE_AGENT);
  __syncthreads();
  if (ticket == gridDim.x - 1 && tid < G) {
    float s = __hip_atomic_load(&gsum[tid], __ATOMIC_RELAXED, __HIP_MEMORY_SCOPE_AGENT);
    float c = __hip_atomic_load(&gcnt[tid], __ATOMIC_RELAXED, __HIP_MEMORY_SCOPE_AGENT);
    out[tid] = fmaxf(s / fmaxf(c, 1.f) + bo[0], 0.f);
  }
}

// ---------------- fallback path (guards fail) ----------------

__global__ __launch_bounds__(256) void fb_scatter(const int* __restrict__ ei,
                                                  const float* __restrict__ x,
                                                  float* __restrict__ agg, int E) {
  int t = blockIdx.x * blockDim.x + threadIdx.x;
  if (t < E) atomicAdd(&agg[ei[E + t]], x[ei[t]]);
}

__global__ __launch_bounds__(256) void fb_node(const float* __restrict__ agg,
                                               const int* __restrict__ batch,
                                               const float* __restrict__ Wl,
                                               const float* __restrict__ bl,
                                               const float* __restrict__ Wo,
                                               float* __restrict__ gsum,
                                               float* __restrict__ gcnt, int N, int H) {
  __shared__ float sWl[HMAX], sbl[HMAX], sWo[HMAX];
  __shared__ float ls[GMAX], lc[GMAX];
  int tid = threadIdx.x;
  if (tid < H) { sWl[tid] = Wl[tid]; sbl[tid] = bl[tid]; sWo[tid] = Wo[tid]; }
  if (tid < GMAX) { ls[tid] = 0.f; lc[tid] = 0.f; }
  __syncthreads();
  int i = blockIdx.x * blockDim.x + tid;
  if (i < N) {
    float a = agg[i], f = 0.f;
    for (int k = 0; k < H; ++k) {
      float hh = fmaf(a, sWl[k], sbl[k]);
      f = fmaf(fmaxf(hh, 0.f), sWo[k], f);
    }
    int g = batch[i];
    atomicAdd(&ls[g], f);
    atomicAdd(&lc[g], 1.f);
  }
  __syncthreads();
  if (tid < GMAX && lc[tid] != 0.f) {
    atomicAdd(&gsum[tid], ls[tid]);
    atomicAdd(&gcnt[tid], lc[tid]);
  }
}

__global__ void fb_final(const float* __restrict__ gsum,
                         const float* __restrict__ gcnt,
                         const float* __restrict__ b_out,
                         float* __restrict__ out, int G) {
  int g = blockIdx.x * blockDim.x + threadIdx.x;
  if (g < G) out[g] = fmaxf(gsum[g] / fmaxf(gcnt[g], 1.f) + b_out[0], 0.f);
}

// ---------------- launch ----------------

extern "C" void kernel_launch(void* const* d_in, const int* in_sizes, int n_in,
                              void* d_out, int out_size, void* d_ws, size_t ws_size,
                              hipStream_t stream) {
  const float* x     = (const float*)d_in[0];
  const int*   ei    = (const int*)d_in[1];
  const int*   batch = (const int*)d_in[2];
  const float* Wl    = (const float*)d_in[3];
  const float* bl    = (const float*)d_in[4];
  const float* Wo    = (const float*)d_in[5];
  const float* bo    = (const float*)d_in[6];
  float* out = (float*)d_out;

  int N = in_sizes[0];        // 100000
  int E = in_sizes[1] / 2;    // 3200000
  int H = in_sizes[3];        // 256
  int G = out_size;           // 128

  int RANGE = (N + RNG - 1) / RNG;           // 6250
  int Q     = E >> 2;
  int QpC   = (Q + CHK - 1) / CHK;           // 25000 quads/chunk

  // ws layout (words): gsum[GMAX] | gcnt[GMAX] | done[..] | pad -> HDRW |
  //                    partial[RNG*CHK][RLDS]
  size_t need = ((size_t)HDRW + (size_t)RNG * CHK * RLDS) * 4u;

  if (RANGE <= RLDS && H <= HMAX && G <= GMAX && ws_size >= need && N > 0) {
    float*    w     = (float*)d_ws;
    float*    gsum  = w;
    float*    gcnt  = w + GMAX;
    unsigned* done  = (unsigned*)(w + 2 * GMAX);
    float*    partial = w + HDRW;

    p1_scatter<<<RNG * CHK, BLK1, 0, stream>>>(ei, x, partial, gsum, gcnt,
                                               done, E, N, RANGE, QpC);
    int BPR = (RANGE + 255) / 256;           // blocks per range (25)
    p2_node<<<RNG * BPR, 256, 0, stream>>>(partial, batch, Wl, bl, Wo, bo,
                                           gsum, gcnt, done, out,
                                           N, H, G, RANGE, BPR);
  } else {
    float* agg  = (float*)d_ws;
    float* gsum = agg + N;
    float* gcnt = gsum + GMAX;
    hipMemsetAsync(d_ws, 0, ((size_t)N + 2 * GMAX) * 4u, stream);
    fb_scatter<<<(E + 255) / 256, 256, 0, stream>>>(ei, x, agg, E);
    fb_node<<<(N + 255) / 256, 256, 0, stream>>>(agg, batch, Wl, bl, Wo,
                                                 gsum, gcnt, N, H);
    fb_final<<<1, 256, 0, stream>>>(gsum, gcnt, bo, out, G);
  }
}

// Round 11
// 119.935 us; speedup vs baseline: 1.0876x; 1.0876x over previous
//
#include <hip/hip_runtime.h>

// N=100000, E=3200000, H=256, G=128.
// R17: redundancy-halving test (RNG 8->4). Evidence chain:
//  - R9/R10: global f32 atomics memory-side at ANY scope (~20G/s) -> LDS agg.
//  - R11: grid.sync ~50us -> no fusion; ~88us harness poison fills INSIDE
//    the timed window (fixed tax).
//  - R16: RNG 16 doubled p1 (24->50us) with WRITE halved as predicted ->
//    p1 cost ~ RNG x E dst-scan work (L2-request/issue bound, not traffic);
//    partial-slab traffic is a minor term. Model: p1 ~ 3us x RNG.
// This round: RNG=4, CHK=64 -> RANGE=25000, slab 100KB LDS, 1 block/CU,
// grid 256, 16 waves/CU (50% occ). Halves dst-scan work vs R15 best; partial
// traffic unchanged (25.6MB each way). Discriminates throughput-bound
// (p1 halves) vs latency-bound (flat -> revert R15, declare floor).
//  P1: block (r,j) streams edge chunk j, filters dst in range r (1-compare
//      unsigned test; per-quad any-pass 68% -> src quad predicated),
//      acc[dst-lo] += x[src] (LDS f32 atomics), slab -> partial[r*CHK+j].
//      Block 0 zeroes header. Chunk affinity: XCD = j%8 (64%8==0);
//      per-XCD dst footprint 8 x 400KB = 3.2MB < 4MB L2.
//  P2: a = sum_j partial[r][j][li] (64 coalesced strided reads), collapsed
//      MLP f(a)=sum_k relu(a*Wl[k]+bl[k])*Wo[k], per-graph LDS pooling,
//      sparse device atomics, ticket epilogue -> relu(mean + b_out).

#define GMAX 128       // max graphs
#define HMAX 256       // max hidden dim
#define RNG  4         // node ranges (LDS-sized)
#define CHK  64        // edge chunks (%8==0 for XCD affinity; grid=256)
#define BLK1 1024      // p1 threads (16 waves; 1 block/CU = 50% occ)
#define RLDS 25024     // LDS accumulator words per range (>= ceil(N/RNG), %64==0)
#define HDRW 272       // header words (gsum,gcnt,done + pad to 16B)

// ---------------- main path ----------------

__global__ __launch_bounds__(BLK1, 4) void p1_scatter(
    const int* __restrict__ ei, const float* __restrict__ x,
    float* __restrict__ partial, float* __restrict__ gsum,
    float* __restrict__ gcnt, unsigned* __restrict__ done,
    int E, int N, int RANGE, int QpC) {
  __shared__ __align__(16) float acc[RLDS];
  int tid = threadIdx.x, blk = blockIdx.x;
  int r = blk / CHK;         // node range id   [0,RNG)
  int j = blk % CHK;         // edge chunk id   [0,CHK) -> XCD = j%8
  for (int i = tid; i < RLDS; i += BLK1) acc[i] = 0.f;
  if (blk == 0) {            // zero epilogue state for P2 (ws is poisoned)
    if (tid < GMAX) { gsum[tid] = 0.f; gcnt[tid] = 0.f; }
    if (tid == 0) done[0] = 0u;
  }
  __syncthreads();

  int lo = r * RANGE;
  unsigned span = (unsigned)(min(lo + RANGE, N) - lo);
  int Q = E >> 2;
  int q0 = j * QpC, q1 = min(q0 + QpC, Q);
  const int4* s4 = (const int4*)ei;
  const int4* d4 = (const int4*)(ei + E);
#pragma unroll 4
  for (int q = q0 + tid; q < q1; q += BLK1) {
    int4 d = d4[q];
    unsigned ux = (unsigned)(d.x - lo), uy = (unsigned)(d.y - lo);
    unsigned uz = (unsigned)(d.z - lo), uw = (unsigned)(d.w - lo);
    if ((ux < span) | (uy < span) | (uz < span) | (uw < span)) {
      int4 s = s4[q];        // src quad only when some lane-edge passes (68%)
      if (ux < span) atomicAdd(&acc[ux], x[s.x]);
      if (uy < span) atomicAdd(&acc[uy], x[s.y]);
      if (uz < span) atomicAdd(&acc[uz], x[s.z]);
      if (uw < span) atomicAdd(&acc[uw], x[s.w]);
    }
  }
  if (j == 0) {              // tail edges (E % 4): the RNG j==0 blocks filter
    for (int e = (Q << 2) + tid; e < E; e += BLK1) {
      unsigned u = (unsigned)(ei[E + e] - lo);
      if (u < span) atomicAdd(&acc[u], x[ei[e]]);
    }
  }
  __syncthreads();

  // coalesced slab dump (full RLDS incl zero pad; P2 reads only li < RANGE)
  float4* dst = (float4*)(partial + (size_t)blk * RLDS);
  const float4* a4 = (const float4*)acc;
  for (int i = tid; i < RLDS / 4; i += BLK1) dst[i] = a4[i];
}

__global__ __launch_bounds__(256, 4) void p2_node(
    const float* __restrict__ partial, const int* __restrict__ batch,
    const float* __restrict__ Wl, const float* __restrict__ bl,
    const float* __restrict__ Wo, const float* __restrict__ bo,
    float* __restrict__ gsum, float* __restrict__ gcnt,
    unsigned* __restrict__ done, float* __restrict__ out,
    int N, int H, int G, int RANGE, int BPR) {
  __shared__ float sWl[HMAX], sbl[HMAX], sWo[HMAX];
  __shared__ float ls[GMAX], lc[GMAX];
  __shared__ unsigned ticket;
  int tid = threadIdx.x, blk = blockIdx.x;
  if (tid < H) { sWl[tid] = Wl[tid]; sbl[tid] = bl[tid]; sWo[tid] = Wo[tid]; }
  if (tid < GMAX) { ls[tid] = 0.f; lc[tid] = 0.f; }
  __syncthreads();

  int r = blk / BPR;
  int li = (blk % BPR) * 256 + tid;
  int node = r * RANGE + li;
  if (li < RANGE && node < N) {
    // CHK-way partial sum: coalesced across lanes, 16-deep ILP across slabs
    const float* p = partial + (size_t)(r * CHK) * RLDS + li;
    float a = 0.f;
#pragma unroll 16
    for (int c = 0; c < CHK; ++c) a += p[(size_t)c * RLDS];
    float f = 0.f;
#pragma unroll 8
    for (int k = 0; k < H; ++k) {
      float hh = fmaf(a, sWl[k], sbl[k]);
      f = fmaf(fmaxf(hh, 0.f), sWo[k], f);
    }
    int g = batch[node];
    atomicAdd(&ls[g], f);
    atomicAdd(&lc[g], 1.f);
  }
  __syncthreads();
  if (tid < GMAX && lc[tid] != 0.f) {
    atomicAdd(&gsum[tid], ls[tid]);   // sparse: batch sorted -> ~1-2 graphs/blk
    atomicAdd(&gcnt[tid], lc[tid]);
  }
  __syncthreads();
  if (tid == 0)
    ticket = __hip_atomic_fetch_add(done, 1u, __ATOMIC_ACQ_REL,
                                    __HIP_MEMORY_SCOPE_AGENT);
  __syncthreads();
  if (ticket == gridDim.x - 1 && tid < G) {
    float s = __hip_atomic_load(&gsum[tid], __ATOMIC_RELAXED, __HIP_MEMORY_SCOPE_AGENT);
    float c = __hip_atomic_load(&gcnt[tid], __ATOMIC_RELAXED, __HIP_MEMORY_SCOPE_AGENT);
    out[tid] = fmaxf(s / fmaxf(c, 1.f) + bo[0], 0.f);
  }
}

// ---------------- fallback path (guards fail) ----------------

__global__ __launch_bounds__(256) void fb_scatter(const int* __restrict__ ei,
                                                  const float* __restrict__ x,
                                                  float* __restrict__ agg, int E) {
  int t = blockIdx.x * blockDim.x + threadIdx.x;
  if (t < E) atomicAdd(&agg[ei[E + t]], x[ei[t]]);
}

__global__ __launch_bounds__(256) void fb_node(const float* __restrict__ agg,
                                               const int* __restrict__ batch,
                                               const float* __restrict__ Wl,
                                               const float* __restrict__ bl,
                                               const float* __restrict__ Wo,
                                               float* __restrict__ gsum,
                                               float* __restrict__ gcnt, int N, int H) {
  __shared__ float sWl[HMAX], sbl[HMAX], sWo[HMAX];
  __shared__ float ls[GMAX], lc[GMAX];
  int tid = threadIdx.x;
  if (tid < H) { sWl[tid] = Wl[tid]; sbl[tid] = bl[tid]; sWo[tid] = Wo[tid]; }
  if (tid < GMAX) { ls[tid] = 0.f; lc[tid] = 0.f; }
  __syncthreads();
  int i = blockIdx.x * blockDim.x + tid;
  if (i < N) {
    float a = agg[i], f = 0.f;
    for (int k = 0; k < H; ++k) {
      float hh = fmaf(a, sWl[k], sbl[k]);
      f = fmaf(fmaxf(hh, 0.f), sWo[k], f);
    }
    int g = batch[i];
    atomicAdd(&ls[g], f);
    atomicAdd(&lc[g], 1.f);
  }
  __syncthreads();
  if (tid < GMAX && lc[tid] != 0.f) {
    atomicAdd(&gsum[tid], ls[tid]);
    atomicAdd(&gcnt[tid], lc[tid]);
  }
}

__global__ void fb_final(const float* __restrict__ gsum,
                         const float* __restrict__ gcnt,
                         const float* __restrict__ b_out,
                         float* __restrict__ out, int G) {
  int g = blockIdx.x * blockDim.x + threadIdx.x;
  if (g < G) out[g] = fmaxf(gsum[g] / fmaxf(gcnt[g], 1.f) + b_out[0], 0.f);
}

// ---------------- launch ----------------

extern "C" void kernel_launch(void* const* d_in, const int* in_sizes, int n_in,
                              void* d_out, int out_size, void* d_ws, size_t ws_size,
                              hipStream_t stream) {
  const float* x     = (const float*)d_in[0];
  const int*   ei    = (const int*)d_in[1];
  const int*   batch = (const int*)d_in[2];
  const float* Wl    = (const float*)d_in[3];
  const float* bl    = (const float*)d_in[4];
  const float* Wo    = (const float*)d_in[5];
  const float* bo    = (const float*)d_in[6];
  float* out = (float*)d_out;

  int N = in_sizes[0];        // 100000
  int E = in_sizes[1] / 2;    // 3200000
  int H = in_sizes[3];        // 256
  int G = out_size;           // 128

  int RANGE = (N + RNG - 1) / RNG;           // 25000
  int Q     = E >> 2;
  int QpC   = (Q + CHK - 1) / CHK;           // 12500 quads/chunk

  // ws layout (words): gsum[GMAX] | gcnt[GMAX] | done[..] | pad -> HDRW |
  //                    partial[RNG*CHK][RLDS]
  size_t need = ((size_t)HDRW + (size_t)RNG * CHK * RLDS) * 4u;

  if (RANGE <= RLDS && H <= HMAX && G <= GMAX && ws_size >= need && N > 0) {
    float*    w     = (float*)d_ws;
    float*    gsum  = w;
    float*    gcnt  = w + GMAX;
    unsigned* done  = (unsigned*)(w + 2 * GMAX);
    float*    partial = w + HDRW;

    p1_scatter<<<RNG * CHK, BLK1, 0, stream>>>(ei, x, partial, gsum, gcnt,
                                               done, E, N, RANGE, QpC);
    int BPR = (RANGE + 255) / 256;           // blocks per range (98)
    p2_node<<<RNG * BPR, 256, 0, stream>>>(partial, batch, Wl, bl, Wo, bo,
                                           gsum, gcnt, done, out,
                                           N, H, G, RANGE, BPR);
  } else {
    float* agg  = (float*)d_ws;
    float* gsum = agg + N;
    float* gcnt = gsum + GMAX;
    hipMemsetAsync(d_ws, 0, ((size_t)N + 2 * GMAX) * 4u, stream);
    fb_scatter<<<(E + 255) / 256, 256, 0, stream>>>(ei, x, agg, E);
    fb_node<<<(N + 255) / 256, 256, 0, stream>>>(agg, batch, Wl, bl, Wo,
                                                 gsum, gcnt, N, H);
    fb_final<<<1, 256, 0, stream>>>(gsum, gcnt, bo, out, G);
  }
}

// Round 12
// 118.195 us; speedup vs baseline: 1.1036x; 1.0147x over previous
//
#include <hip/hip_runtime.h>

// N=100000, E=3200000, H=256, G=128.
// R18: manual 4-deep software pipeline in p1. Evidence chain:
//  - R9/R10: global f32 atomics memory-side at ANY scope -> LDS agg only.
//  - R11: grid.sync ~50us -> no fusion; ~88us harness poison fills INSIDE
//    the timed window (fixed tax, independent of our ws usage).
//  - R16: p1 cost ~ RNG x E (redundant dst scans), partial traffic minor.
//  - R17: RNG 4 @ 50% occ == RNG 8 @ 100% occ (flat 119.8/119.9) ->
//    latency-hiding-limited; work and waves trade 1:1.
//  - R16 counters: p1 VGPR_Count = 12 -> compiler SERIALIZED the unroll-4
//    loop (4 in-flight int4 dst+src quads need >=40 VGPR). Per-wave ILP is
//    the missing lever, not occupancy.
// This round (config = R15 best: RNG=8, CHK=64, BLK1=1024, 2 blk/CU):
// hand-pipelined inner loop: 4 named dst-quad loads issued back-to-back,
// then 4 predicated src-quad loads, then 16 gathers + LDS atomics.
// launch_bounds(1024,8) -> 64-VGPR budget for the pipeline.
//  P1: block (r,j) streams edge chunk j, filters dst in range r (1-compare
//      unsigned test), acc[dst-lo] += x[src] (LDS f32 atomics), slab ->
//      partial[r*CHK+j] coalesced. Block 0 zeroes header for P2.
//      Chunk affinity: XCD = j%8; per-XCD dst footprint 3.2MB < 4MB L2.
//  P2: a = sum_j partial[r][j][li] (64 coalesced strided reads), collapsed
//      MLP f(a)=sum_k relu(a*Wl[k]+bl[k])*Wo[k], per-graph LDS pooling,
//      sparse device atomics, ticket epilogue -> relu(mean + b_out).

#define GMAX 128       // max graphs
#define HMAX 256       // max hidden dim
#define RNG  8         // node ranges (LDS-sized)
#define CHK  64        // edge chunks (%8==0 for XCD affinity; grid=512)
#define BLK1 1024      // p1 threads (16 waves; 2 blocks/CU = 32 waves = 100%)
#define RLDS 12544     // LDS accumulator words per range (>= ceil(N/RNG), %64==0)
#define HDRW 272       // header words (gsum,gcnt,done + pad to 16B)

// range-test a dst quad
#define RTEST(dd, ax, ay, az, aw, anyp)                         \
  ax = (unsigned)(dd.x - lo); ay = (unsigned)(dd.y - lo);       \
  az = (unsigned)(dd.z - lo); aw = (unsigned)(dd.w - lo);       \
  anyp = (ax < span) | (ay < span) | (az < span) | (aw < span);

// gather + LDS atomic for the passing lanes of a quad
#define RPROC(ss, ax, ay, az, aw)                               \
  if (ax < span) atomicAdd(&acc[ax], x[ss.x]);                  \
  if (ay < span) atomicAdd(&acc[ay], x[ss.y]);                  \
  if (az < span) atomicAdd(&acc[az], x[ss.z]);                  \
  if (aw < span) atomicAdd(&acc[aw], x[ss.w]);

// ---------------- main path ----------------

__global__ __launch_bounds__(BLK1, 8) void p1_scatter(
    const int* __restrict__ ei, const float* __restrict__ x,
    float* __restrict__ partial, float* __restrict__ gsum,
    float* __restrict__ gcnt, unsigned* __restrict__ done,
    int E, int N, int RANGE, int QpC) {
  __shared__ __align__(16) float acc[RLDS];
  int tid = threadIdx.x, blk = blockIdx.x;
  int r = blk / CHK;         // node range id   [0,RNG)
  int j = blk % CHK;         // edge chunk id   [0,CHK) -> XCD = j%8
  for (int i = tid; i < RLDS; i += BLK1) acc[i] = 0.f;
  if (blk == 0) {            // zero epilogue state for P2 (ws is poisoned)
    if (tid < GMAX) { gsum[tid] = 0.f; gcnt[tid] = 0.f; }
    if (tid == 0) done[0] = 0u;
  }
  __syncthreads();

  int lo = r * RANGE;
  unsigned span = (unsigned)(min(lo + RANGE, N) - lo);
  int Q = E >> 2;
  int q0 = j * QpC, q1 = min(q0 + QpC, Q);
  const int4* s4 = (const int4*)ei;
  const int4* d4 = (const int4*)(ei + E);

  int q = q0 + tid;
  // main: 4 strided quads in flight (explicit pipeline; compiler-proof ILP)
  while (q + 3 * BLK1 < q1) {
    int4 d0 = d4[q];
    int4 d1 = d4[q + BLK1];
    int4 d2 = d4[q + 2 * BLK1];
    int4 d3 = d4[q + 3 * BLK1];
    unsigned a0x, a0y, a0z, a0w, a1x, a1y, a1z, a1w;
    unsigned a2x, a2y, a2z, a2w, a3x, a3y, a3z, a3w;
    bool p0, p1, p2, p3;
    RTEST(d0, a0x, a0y, a0z, a0w, p0)
    RTEST(d1, a1x, a1y, a1z, a1w, p1)
    RTEST(d2, a2x, a2y, a2z, a2w, p2)
    RTEST(d3, a3x, a3y, a3z, a3w, p3)
    int4 s0, s1, s2, s3;
    if (p0) s0 = s4[q];
    if (p1) s1 = s4[q + BLK1];
    if (p2) s2 = s4[q + 2 * BLK1];
    if (p3) s3 = s4[q + 3 * BLK1];
    if (p0) { RPROC(s0, a0x, a0y, a0z, a0w) }
    if (p1) { RPROC(s1, a1x, a1y, a1z, a1w) }
    if (p2) { RPROC(s2, a2x, a2y, a2z, a2w) }
    if (p3) { RPROC(s3, a3x, a3y, a3z, a3w) }
    q += 4 * BLK1;
  }
  // remainder
  while (q < q1) {
    int4 d0 = d4[q];
    unsigned a0x, a0y, a0z, a0w;
    bool p0;
    RTEST(d0, a0x, a0y, a0z, a0w, p0)
    if (p0) {
      int4 s0 = s4[q];
      RPROC(s0, a0x, a0y, a0z, a0w)
    }
    q += BLK1;
  }
  if (j == 0) {              // tail edges (E % 4): the RNG j==0 blocks filter
    for (int e = (Q << 2) + tid; e < E; e += BLK1) {
      unsigned u = (unsigned)(ei[E + e] - lo);
      if (u < span) atomicAdd(&acc[u], x[ei[e]]);
    }
  }
  __syncthreads();

  // coalesced slab dump (full RLDS incl zero pad; P2 reads only li < RANGE)
  float4* dst = (float4*)(partial + (size_t)blk * RLDS);
  const float4* a4 = (const float4*)acc;
  for (int i = tid; i < RLDS / 4; i += BLK1) dst[i] = a4[i];
}

__global__ __launch_bounds__(256, 4) void p2_node(
    const float* __restrict__ partial, const int* __restrict__ batch,
    const float* __restrict__ Wl, const float* __restrict__ bl,
    const float* __restrict__ Wo, const float* __restrict__ bo,
    float* __restrict__ gsum, float* __restrict__ gcnt,
    unsigned* __restrict__ done, float* __restrict__ out,
    int N, int H, int G, int RANGE, int BPR) {
  __shared__ float sWl[HMAX], sbl[HMAX], sWo[HMAX];
  __shared__ float ls[GMAX], lc[GMAX];
  __shared__ unsigned ticket;
  int tid = threadIdx.x, blk = blockIdx.x;
  if (tid < H) { sWl[tid] = Wl[tid]; sbl[tid] = bl[tid]; sWo[tid] = Wo[tid]; }
  if (tid < GMAX) { ls[tid] = 0.f; lc[tid] = 0.f; }
  __syncthreads();

  int r = blk / BPR;
  int li = (blk % BPR) * 256 + tid;
  int node = r * RANGE + li;
  if (li < RANGE && node < N) {
    // CHK-way partial sum: coalesced across lanes, 16-deep ILP across slabs
    const float* p = partial + (size_t)(r * CHK) * RLDS + li;
    float a = 0.f;
#pragma unroll 16
    for (int c = 0; c < CHK; ++c) a += p[(size_t)c * RLDS];
    float f = 0.f;
#pragma unroll 8
    for (int k = 0; k < H; ++k) {
      float hh = fmaf(a, sWl[k], sbl[k]);
      f = fmaf(fmaxf(hh, 0.f), sWo[k], f);
    }
    int g = batch[node];
    atomicAdd(&ls[g], f);
    atomicAdd(&lc[g], 1.f);
  }
  __syncthreads();
  if (tid < GMAX && lc[tid] != 0.f) {
    atomicAdd(&gsum[tid], ls[tid]);   // sparse: batch sorted -> ~1-2 graphs/blk
    atomicAdd(&gcnt[tid], lc[tid]);
  }
  __syncthreads();
  if (tid == 0)
    ticket = __hip_atomic_fetch_add(done, 1u, __ATOMIC_ACQ_REL,
                                    __HIP_MEMORY_SCOPE_AGENT);
  __syncthreads();
  if (ticket == gridDim.x - 1 && tid < G) {
    float s = __hip_atomic_load(&gsum[tid], __ATOMIC_RELAXED, __HIP_MEMORY_SCOPE_AGENT);
    float c = __hip_atomic_load(&gcnt[tid], __ATOMIC_RELAXED, __HIP_MEMORY_SCOPE_AGENT);
    out[tid] = fmaxf(s / fmaxf(c, 1.f) + bo[0], 0.f);
  }
}

// ---------------- fallback path (guards fail) ----------------

__global__ __launch_bounds__(256) void fb_scatter(const int* __restrict__ ei,
                                                  const float* __restrict__ x,
                                                  float* __restrict__ agg, int E) {
  int t = blockIdx.x * blockDim.x + threadIdx.x;
  if (t < E) atomicAdd(&agg[ei[E + t]], x[ei[t]]);
}

__global__ __launch_bounds__(256) void fb_node(const float* __restrict__ agg,
                                               const int* __restrict__ batch,
                                               const float* __restrict__ Wl,
                                               const float* __restrict__ bl,
                                               const float* __restrict__ Wo,
                                               float* __restrict__ gsum,
                                               float* __restrict__ gcnt, int N, int H) {
  __shared__ float sWl[HMAX], sbl[HMAX], sWo[HMAX];
  __shared__ float ls[GMAX], lc[GMAX];
  int tid = threadIdx.x;
  if (tid < H) { sWl[tid] = Wl[tid]; sbl[tid] = bl[tid]; sWo[tid] = Wo[tid]; }
  if (tid < GMAX) { ls[tid] = 0.f; lc[tid] = 0.f; }
  __syncthreads();
  int i = blockIdx.x * blockDim.x + tid;
  if (i < N) {
    float a = agg[i], f = 0.f;
    for (int k = 0; k < H; ++k) {
      float hh = fmaf(a, sWl[k], sbl[k]);
      f = fmaf(fmaxf(hh, 0.f), sWo[k], f);
    }
    int g = batch[i];
    atomicAdd(&ls[g], f);
    atomicAdd(&lc[g], 1.f);
  }
  __syncthreads();
  if (tid < GMAX && lc[tid] != 0.f) {
    atomicAdd(&gsum[tid], ls[tid]);
    atomicAdd(&gcnt[tid], lc[tid]);
  }
}

__global__ void fb_final(const float* __restrict__ gsum,
                         const float* __restrict__ gcnt,
                         const float* __restrict__ b_out,
                         float* __restrict__ out, int G) {
  int g = blockIdx.x * blockDim.x + threadIdx.x;
  if (g < G) out[g] = fmaxf(gsum[g] / fmaxf(gcnt[g], 1.f) + b_out[0], 0.f);
}

// ---------------- launch ----------------

extern "C" void kernel_launch(void* const* d_in, const int* in_sizes, int n_in,
                              void* d_out, int out_size, void* d_ws, size_t ws_size,
                              hipStream_t stream) {
  const float* x     = (const float*)d_in[0];
  const int*   ei    = (const int*)d_in[1];
  const int*   batch = (const int*)d_in[2];
  const float* Wl    = (const float*)d_in[3];
  const float* bl    = (const float*)d_in[4];
  const float* Wo    = (const float*)d_in[5];
  const float* bo    = (const float*)d_in[6];
  float* out = (float*)d_out;

  int N = in_sizes[0];        // 100000
  int E = in_sizes[1] / 2;    // 3200000
  int H = in_sizes[3];        // 256
  int G = out_size;           // 128

  int RANGE = (N + RNG - 1) / RNG;           // 12500
  int Q     = E >> 2;
  int QpC   = (Q + CHK - 1) / CHK;           // 12500 quads/chunk

  // ws layout (words): gsum[GMAX] | gcnt[GMAX] | done[..] | pad -> HDRW |
  //                    partial[RNG*CHK][RLDS]
  size_t need = ((size_t)HDRW + (size_t)RNG * CHK * RLDS) * 4u;

  if (RANGE <= RLDS && H <= HMAX && G <= GMAX && ws_size >= need && N > 0) {
    float*    w     = (float*)d_ws;
    float*    gsum  = w;
    float*    gcnt  = w + GMAX;
    unsigned* done  = (unsigned*)(w + 2 * GMAX);
    float*    partial = w + HDRW;

    p1_scatter<<<RNG * CHK, BLK1, 0, stream>>>(ei, x, partial, gsum, gcnt,
                                               done, E, N, RANGE, QpC);
    int BPR = (RANGE + 255) / 256;           // blocks per range (49)
    p2_node<<<RNG * BPR, 256, 0, stream>>>(partial, batch, Wl, bl, Wo, bo,
                                           gsum, gcnt, done, out,
                                           N, H, G, RANGE, BPR);
  } else {
    float* agg  = (float*)d_ws;
    float* gsum = agg + N;
    float* gcnt = gsum + GMAX;
    hipMemsetAsync(d_ws, 0, ((size_t)N + 2 * GMAX) * 4u, stream);
    fb_scatter<<<(E + 255) / 256, 256, 0, stream>>>(ei, x, agg, E);
    fb_node<<<(N + 255) / 256, 256, 0, stream>>>(agg, batch, Wl, bl, Wo,
                                                 gsum, gcnt, N, H);
    fb_final<<<1, 256, 0, stream>>>(gsum, gcnt, bo, out, G);
  }
}